// Round 12
// baseline (452.515 us; speedup 1.0000x reference)
//
#include <hip/hip_runtime.h>
#include <math.h>

typedef _Float16 f16;
typedef f16 f16x8 __attribute__((ext_vector_type(8)));
typedef f16 f16x2 __attribute__((ext_vector_type(2)));
typedef float f32x4 __attribute__((ext_vector_type(4)));

// ---------------- problem constants ----------------
#define BB 2
#define QQ 2048
#define CF 576
#define NOFF 36
#define NBQ (BB*QQ)          // 4096
#define NROWS (NOFF*NBQ)     // 147456  (row R = bq*36 + n)
#define FEAT_ELEMS (BB*66*66*64)
#define MROWS 48             // rows per workgroup (spans exactly 2 bq segments)
#define NWG (NROWS/MROWS)    // 3072
#define PITCHB 640           // bytes per LDS X row (320 halfs)

// ---------------- kernel 1: conv 3x3, 3->64, padded NHWC, fp16 out ----------------
__global__ __launch_bounds__(256) void k_conv(const float* __restrict__ inp,
                                              const float* __restrict__ ew,
                                              const float* __restrict__ eb,
                                              f16* __restrict__ feat) {
    int idx = blockIdx.x * 256 + threadIdx.x;
    if (idx >= FEAT_ELEMS) return;
    int c = idx & 63;
    int t = idx >> 6;
    int x = t % 66; t /= 66;
    int y = t % 66;
    int b = t / 66;
    float v = 0.f;
    if (y >= 1 && y <= 64 && x >= 1 && x <= 64) {
        int yr = y - 1, xr = x - 1;
        v = eb[c];
        #pragma unroll
        for (int i = 0; i < 3; ++i)
            #pragma unroll
            for (int ky = 0; ky < 3; ++ky) {
                int yy = yr + ky - 1;
                if (yy < 0 || yy > 63) continue;
                #pragma unroll
                for (int kx = 0; kx < 3; ++kx) {
                    int xx = xr + kx - 1;
                    if (xx < 0 || xx > 63) continue;
                    v = fmaf(inp[((b*3 + i)*64 + yy)*64 + xx],
                             ew[((c*3 + i)*3 + ky)*3 + kx], v);
                }
            }
    }
    feat[idx] = (f16)v;
}

// ---------------- kernel 2: weight convert fp32 -> fp16, k-step-major ----------------
// layout [ks][N][32]: element (ks,col,kk) at (ks*N + col)*32 + kk, k = ks*32+kk
__global__ __launch_bounds__(256) void k_wcvt(const float* __restrict__ w0,
                                              const float* __restrict__ w1,
                                              const float* __restrict__ w2,
                                              const float* __restrict__ w3,
                                              const float* __restrict__ w4,
                                              f16* __restrict__ wt0, f16* __restrict__ wt1,
                                              f16* __restrict__ wt2, f16* __restrict__ wt3,
                                              f16* __restrict__ wt4) {
    int i = blockIdx.x * 256 + threadIdx.x;
    if (i < 19*256*32) {
        int kk = i & 31, col = (i >> 5) & 255, ks = i >> 13;
        int k = ks*32 + kk;
        wt0[i] = (f16)((k < 578) ? w0[k*256 + col] : 0.f);
        return;
    }
    i -= 19*256*32;
    if (i < 3*65536) {
        int l = i >> 16, j = i & 65535;
        int kk = j & 31, col = (j >> 5) & 255, ks = j >> 13;
        int k = ks*32 + kk;
        const float* w = (l == 0) ? w1 : (l == 1) ? w2 : w3;
        f16* wt = (l == 0) ? wt1 : (l == 1) ? wt2 : wt3;
        wt[j] = (f16)w[k*256 + col];
        return;
    }
    i -= 3*65536;
    if (i < 8192) {
        int kk = i & 31, col = (i >> 5) & 31, ks = i >> 10;
        int k = ks*32 + kk;
        wt4[i] = (f16)((col < 27) ? w4[k*27 + col] : 0.f);
    }
}

// ---------------- kernel 3: per-row prep (R = bq*36 + n) ----------------
__global__ __launch_bounds__(256) void k_prep(const float* __restrict__ coord,
                                              float* __restrict__ qc0w,
                                              float* __restrict__ qc1w,
                                              float* __restrict__ areaw,
                                              int* __restrict__ iposw) {
    int R = blockIdx.x * 256 + threadIdx.x;
    if (R >= NROWS) return;
    int bq = R / 36, n = R - bq*36;
    const float offs[6] = {-3.f, -2.f, -1.f, 1.f, 2.f, 3.f};
    float vx = offs[n / 6];
    float vy = offs[n % 6];
    const float* cp = coord + bq * 18;
    float cc0 = cp[8] + vx * (1.0f/64.0f) + 1e-6f;
    float cc1 = cp[9] + vy * (1.0f/64.0f) + 1e-6f;
    cc0 = fminf(fmaxf(cc0, -1.f + 1e-6f), 1.f - 1e-6f);
    cc1 = fminf(fmaxf(cc1, -1.f + 1e-6f), 1.f - 1e-6f);
    int iy = (int)rintf(((cc0 + 1.f) * 64.f - 1.f) * 0.5f);
    int ix = (int)rintf(((cc1 + 1.f) * 64.f - 1.f) * 0.5f);
    iy = min(max(iy, 0), 63);
    ix = min(max(ix, 0), 63);
    float qc0 = -1.f + (2.f * (float)iy + 1.f) * (1.0f/64.0f);
    float qc1 = -1.f + (2.f * (float)ix + 1.f) * (1.0f/64.0f);
    float rel0 = (cp[0] - qc0) * 4096.f;
    float rel1 = (cp[1] - qc1);
    qc0w[R] = qc0;
    qc1w[R] = qc1;
    areaw[R] = fabsf(rel0 * rel1) + 1e-9f;
    int b = bq >> 11;
    iposw[R] = ((b*66 + iy)*66 + ix) * 64;
}

// ---------------- kernel 4: per-bq weights (perm + normalize) ----------------
__global__ __launch_bounds__(256) void k_wgt(const float* __restrict__ areaw,
                                             float* __restrict__ wgtw) {
    int bq = blockIdx.x * 256 + threadIdx.x;
    if (bq >= NBQ) return;
    float a[36];
    float tot = 0.f;
    #pragma unroll
    for (int n = 0; n < 36; ++n) { a[n] = areaw[bq*36 + n]; tot += a[n]; }
    #pragma unroll
    for (int n = 0; n < 36; ++n) {
        int pn = (n < 4) ? 3 - n : n;
        wgtw[bq*36 + n] = a[pn] / tot;
    }
}

// ---------------- build X chunk into LDS (hw sin/cos, fp16 feat) ----------------
template <int COLS2, int JOFF>
__device__ __forceinline__ void buildX(f16* sX, const f16* __restrict__ feat,
                                       const int* s_ipos, const float* s_crd,
                                       const float* s_qc0, const float* s_qc1,
                                       const float* s_cx, const float* s_cy,
                                       const float* s_div, int tid) {
    constexpr int NPAIR = MROWS * COLS2;
    #pragma unroll 2
    for (int p = tid; p < NPAIR; p += 512) {
        int r = p / COLS2;                 // division by compile-time constant
        int j = JOFF + ((p - r * COLS2) << 1);
        float v0, v1;
        if (j < CF) {
            int c0 = j / 9,  s0 = j  - c0*9;
            int j1 = j + 1;
            int c1 = j1 / 9, s1 = j1 - c1*9;
            int ip = s_ipos[r];
            float f0 = (float)feat[ip + ((s0/3)*66 + (s0 - (s0/3)*3))*64 + c0];
            float f1 = (float)feat[ip + ((s1/3)*66 + (s1 - (s1/3)*3))*64 + c1];
            int d  = j & 63;
            int pl = j >> 6;
            int h2 = d >> 5;
            float qc = h2 ? s_qc1[r] : s_qc0[r];
            float sc = h2 ? 1.f : 4096.f;
            float comp = (s_crd[r*18 + 2*pl + h2] - qc) * sc;
            float arg  = comp * s_div[(d & 31) >> 1];
            // hw sin/cos: reduce to revolutions (same numerics as R5/R6)
            float rev = arg * 0.15915494309189535f;
            rev = rev - rintf(rev);
            v0 = f0 + __builtin_amdgcn_sinf(rev);
            v1 = f1 + __builtin_amdgcn_cosf(rev);
        } else if (j == CF) {
            v0 = s_cx[r]; v1 = s_cy[r];
        } else {
            v0 = 0.f; v1 = 0.f;
        }
        uint off = (uint)(r*PITCHB + (j - JOFF)*2);
        off ^= (uint)((r & 7) << 4);
        f16x2 hv = { (f16)v0, (f16)v1 };
        *(f16x2*)((char*)sX + off) = hv;
    }
}

// ---------------- direct-load GEMM (layer 4 only, tiny) ----------------
template <int NKS, int NNT, int PITCHC>
__device__ __forceinline__ void gemmT(const f16* sX, const f16* __restrict__ Wt,
                                      int colbase, int lg,
                                      const uint (&abase)[3], uint aswz,
                                      f32x4 (&acc)[3][NNT]) {
    #pragma unroll
    for (int ks = 0; ks < NKS; ++ks) {
        f16x8 a[3], b[NNT];
        #pragma unroll
        for (int nt = 0; nt < NNT; ++nt)
            b[nt] = *(const f16x8*)(Wt + (ks*PITCHC + colbase + nt*16)*32 + lg*8);
        #pragma unroll
        for (int mt = 0; mt < 3; ++mt)
            a[mt] = *(const f16x8*)((const char*)sX + ((abase[mt] + (uint)(ks*64)) ^ aswz));
        #pragma unroll
        for (int mt = 0; mt < 3; ++mt)
            #pragma unroll
            for (int nt = 0; nt < NNT; ++nt)
                acc[mt][nt] = __builtin_amdgcn_mfma_f32_16x16x32_f16(a[mt], b[nt], acc[mt][nt], 0, 0, 0);
    }
}

// ---------------- kernel 5: fused MFMA MLP, LDS-staged B, 8 waves ----------------
// 512 threads, wave wc=tid>>6 owns all 48 rows x 32 cols (cols wc*32..wc*32+31).
__global__ __launch_bounds__(512, 4) void k_mlp(
    const float* __restrict__ coord, const float* __restrict__ cellp,
    const f16* __restrict__ feat,
    const float* __restrict__ qc0w, const float* __restrict__ qc1w,
    const float* __restrict__ wgtw, const int* __restrict__ iposw,
    const f16* __restrict__ wt0, const f16* __restrict__ wt1,
    const f16* __restrict__ wt2, const f16* __restrict__ wt3,
    const f16* __restrict__ wt4,
    const float* __restrict__ b0, const float* __restrict__ b1,
    const float* __restrict__ b2, const float* __restrict__ b3,
    const float* __restrict__ b4,
    float* __restrict__ partial)   // [NWG][2][28]
{
    __shared__ f16 sX[MROWS * 320];      // 30720 B, in-place activation buffer
    __shared__ f16 sBB[2][8192];         // 2 x 16 KB B k-step tiles, layout [lg][col][8]
    __shared__ float s_crd[MROWS * 18];
    __shared__ float s_qc0[MROWS], s_qc1[MROWS], s_cx[MROWS], s_cy[MROWS], s_wgt[MROWS];
    __shared__ int   s_ipos[MROWS];
    __shared__ float s_div[16];

    int tid = threadIdx.x;
    int R0  = blockIdx.x * MROWS;

    if (tid < 16) s_div[tid] = expf((float)(2*tid) * -0.28782313662425575f);
    if (tid < MROWS) {
        int R  = R0 + tid;
        int bq = R / 36;
        s_qc0[tid]  = __builtin_nontemporal_load(&qc0w[R]);
        s_qc1[tid]  = __builtin_nontemporal_load(&qc1w[R]);
        s_wgt[tid]  = __builtin_nontemporal_load(&wgtw[R]);
        s_ipos[tid] = __builtin_nontemporal_load(&iposw[R]);
        s_cx[tid]   = cellp[bq*2 + 0] * 64.f;
        s_cy[tid]   = cellp[bq*2 + 1] * 64.f;
    }
    for (int i = tid; i < MROWS*18; i += 512) {
        int r = i / 18, d = i - r*18;
        s_crd[i] = coord[((R0 + r)/36)*18 + d];
    }

    int lane = tid & 63;
    int wc   = tid >> 6;    // wave = col group of 32 (0..7)
    int l15  = lane & 15;
    int lg   = lane >> 4;   // 0..3
    uint aswz = (uint)((lane & 7) << 4);

    uint abase[3];
    #pragma unroll
    for (int mt = 0; mt < 3; ++mt) {
        int row = mt*16 + l15;
        abase[mt] = (uint)(row * PITCHB + lg*16);
    }

    f32x4 acc[3][2];
    auto zacc = [&]() {
        #pragma unroll
        for (int mt = 0; mt < 3; ++mt)
            #pragma unroll
            for (int nt = 0; nt < 2; ++nt)
                #pragma unroll
                for (int i = 0; i < 4; ++i) acc[mt][nt][i] = 0.f;
    };

    // cooperative async stage of one 16 KB B k-step tile: global [ks][col][32] ->
    // LDS chunk c (16 B) at byte c*16 holds global bytes col*64 + lg*16, c = lg*256+col.
    // 512 threads x 2 chunks: chunk = tid + i*512.
    auto stage = [&](f16* dst, const f16* __restrict__ Wt, int ks) {
        const char* g = (const char*)Wt + (size_t)ks * 16384
                        + (size_t)(tid & 255) * 64 + (size_t)(tid >> 8) * 16;
        char* d = (char*)dst + tid * 16;
        #pragma unroll
        for (int i = 0; i < 2; ++i) {
            __builtin_amdgcn_global_load_lds(
                (const __attribute__((address_space(1))) void*)(g + i*32),
                (__attribute__((address_space(3))) void*)(d + i*8192),
                16, 0, 0);
        }
    };

    // one k-step of MFMA: B frags from staged LDS tile, A frags from sX
    auto computeK = [&](const f16* sB, int lks) {
        f16x8 a[3], b[2];
        #pragma unroll
        for (int nt = 0; nt < 2; ++nt)
            b[nt] = *(const f16x8*)((const char*)sB + lg*4096 + (wc*32 + nt*16 + l15)*16);
        #pragma unroll
        for (int mt = 0; mt < 3; ++mt)
            a[mt] = *(const f16x8*)((const char*)sX + ((abase[mt] + (uint)(lks*64)) ^ aswz));
        #pragma unroll
        for (int mt = 0; mt < 3; ++mt)
            #pragma unroll
            for (int nt = 0; nt < 2; ++nt)
                acc[mt][nt] = __builtin_amdgcn_mfma_f32_16x16x32_f16(a[mt], b[nt], acc[mt][nt], 0, 0, 0);
    };

    // run nks k-steps: stage(ks+1) issued after the per-kstep barrier -> in flight
    // during compute(ks); next barrier's vmcnt drain lands it (T3-lite).
    auto runLayer = [&](const f16* __restrict__ Wt, int gksOff, int nks, int lksOff) {
        stage(sBB[0], Wt, gksOff);
        for (int ks = 0; ks < nks; ++ks) {
            __syncthreads();
            if (ks + 1 < nks) stage(sBB[(ks + 1) & 1], Wt, gksOff + ks + 1);
            computeK(sBB[ks & 1], lksOff + ks);
        }
    };

    // bias + relu + fp16 -> swizzled LDS (in place, after barrier)
    auto epi = [&](const float* __restrict__ bias) {
        #pragma unroll
        for (int nt = 0; nt < 2; ++nt) {
            int col = wc*32 + nt*16 + l15;
            float bv = bias[col];
            #pragma unroll
            for (int mt = 0; mt < 3; ++mt)
                #pragma unroll
                for (int i = 0; i < 4; ++i) {
                    int row = mt*16 + lg*4 + i;
                    float v = fmaxf(acc[mt][nt][i] + bv, 0.f);
                    uint off = (uint)(row*PITCHB + col*2) ^ (uint)((row & 7) << 4);
                    *(f16*)((char*)sX + off) = (f16)v;
                }
        }
    };

    __syncthreads();

    // ---- layer 0 : K = 608, X in two LDS chunks, in-place ----
    zacc();
    buildX<160, 0>(sX, feat, s_ipos, s_crd, s_qc0, s_qc1, s_cx, s_cy, s_div, tid);
    runLayer(wt0, 0, 10, 0);       // loop barrier covers buildX + stage(0)
    __syncthreads();               // all compute done reading X chunk 0
    buildX<144, 320>(sX, feat, s_ipos, s_crd, s_qc0, s_qc1, s_cx, s_cy, s_div, tid);
    runLayer(wt0, 10, 9, 0);
    __syncthreads();
    epi(b0);

    // ---- layers 1..3 : K = 256, in-place ----
    zacc(); runLayer(wt1, 0, 8, 0); __syncthreads(); epi(b1);
    zacc(); runLayer(wt2, 0, 8, 0); __syncthreads(); epi(b2);
    zacc(); runLayer(wt3, 0, 8, 0); __syncthreads(); epi(b3);
    __syncthreads();   // L4 reads sX

    // ---- layer 4 : 256 -> 27 (padded 32), wave 0 only, + weighted segment sums ----
    if (wc == 0) {
        f32x4 a4[3][2];
        #pragma unroll
        for (int mt = 0; mt < 3; ++mt)
            #pragma unroll
            for (int nt = 0; nt < 2; ++nt)
                #pragma unroll
                for (int i = 0; i < 4; ++i) a4[mt][nt][i] = 0.f;
        gemmT<8,2,32>(sX, wt4, l15, lg, abase, aswz, a4);
        // WG covers rows of exactly 2 bq segments: rows [0,split) and [split,48)
        int split = 36 - (R0 % 36);    // R0%36 in {0,12,24} -> split in {36,24,12}
        #pragma unroll
        for (int nt = 0; nt < 2; ++nt) {
            int col = nt*16 + l15;
            float bv = (col < 27) ? b4[col] : 0.f;
            float s0 = 0.f, s1 = 0.f;
            #pragma unroll
            for (int mt = 0; mt < 3; ++mt)
                #pragma unroll
                for (int i = 0; i < 4; ++i) {
                    int row = mt*16 + lg*4 + i;
                    float v = (a4[mt][nt][i] + bv) * s_wgt[row];
                    if (row < split) s0 += v; else s1 += v;
                }
            // reduce across lg groups (lanes +-16, +-32)
            s0 += __shfl_xor(s0, 16, 64);
            s0 += __shfl_xor(s0, 32, 64);
            s1 += __shfl_xor(s1, 16, 64);
            s1 += __shfl_xor(s1, 32, 64);
            if (lg == 0 && col < 27) {
                __builtin_nontemporal_store(s0, &partial[(size_t)blockIdx.x*56 + col]);
                __builtin_nontemporal_store(s1, &partial[(size_t)blockIdx.x*56 + 28 + col]);
            }
        }
    }
}

// ---------------- kernel 6: combine <=2 window partials per bq ----------------
__global__ __launch_bounds__(256) void k_red(const float* __restrict__ partial,
                                             float* __restrict__ out) {
    int i = blockIdx.x * 256 + threadIdx.x;
    if (i >= NBQ * 27) return;
    int bq = i / 27, col = i - bq*27;
    int r_lo = bq * 36;
    int w0 = r_lo / 48, w1 = (r_lo + 35) / 48;
    float s = 0.f;
    for (int w = w0; w <= w1; ++w) {
        int seg = (bq == (w*48)/36) ? 0 : 1;
        s += __builtin_nontemporal_load(&partial[(size_t)w*56 + seg*28 + col]);
    }
    out[i] = s;
}

// ---------------- launch ----------------
extern "C" void kernel_launch(void* const* d_in, const int* in_sizes, int n_in,
                              void* d_out, int out_size, void* d_ws, size_t ws_size,
                              hipStream_t stream) {
    const float* inp   = (const float*)d_in[0];
    const float* coord = (const float*)d_in[1];
    const float* cellp = (const float*)d_in[2];
    const float* enc_w = (const float*)d_in[3];
    const float* enc_b = (const float*)d_in[4];
    const float* w0 = (const float*)d_in[5];
    const float* b0 = (const float*)d_in[6];
    const float* w1 = (const float*)d_in[7];
    const float* b1 = (const float*)d_in[8];
    const float* w2 = (const float*)d_in[9];
    const float* b2 = (const float*)d_in[10];
    const float* w3 = (const float*)d_in[11];
    const float* b3 = (const float*)d_in[12];
    const float* w4 = (const float*)d_in[13];
    const float* b4 = (const float*)d_in[14];
    float* outp = (float*)d_out;

    float* ws    = (float*)d_ws;
    f16*   feat  = (f16*)ws;                         // FEAT_ELEMS halfs
    float* qc0w  = (float*)(feat + FEAT_ELEMS);      // NROWS
    float* qc1w  = qc0w + NROWS;
    float* areaw = qc1w + NROWS;
    float* wgtw  = areaw + NROWS;
    int*   iposw = (int*)(wgtw + NROWS);
    float* partial = (float*)(iposw + NROWS);        // NWG*2*28
    f16*   wt0   = (f16*)(partial + (size_t)NWG*56); // 19*256*32
    f16*   wt1   = wt0 + 19*256*32;
    f16*   wt2   = wt1 + 65536;
    f16*   wt3   = wt2 + 65536;
    f16*   wt4   = wt3 + 65536;                      // 8192

    k_conv<<<(FEAT_ELEMS + 255)/256, 256, 0, stream>>>(inp, enc_w, enc_b, feat);
    k_wcvt<<<1408, 256, 0, stream>>>(w0, w1, w2, w3, w4, wt0, wt1, wt2, wt3, wt4);
    k_prep<<<NROWS/256, 256, 0, stream>>>(coord, qc0w, qc1w, areaw, iposw);
    k_wgt<<<(NBQ + 255)/256, 256, 0, stream>>>(areaw, wgtw);
    k_mlp<<<NWG, 512, 0, stream>>>(coord, cellp, feat, qc0w, qc1w, wgtw, iposw,
                                   wt0, wt1, wt2, wt3, wt4,
                                   b0, b1, b2, b3, b4, partial);
    k_red<<<(NBQ*27 + 255)/256, 256, 0, stream>>>(partial, outp);
}

// Round 13
// 309.161 us; speedup vs baseline: 1.4637x; 1.4637x over previous
//
#include <hip/hip_runtime.h>
#include <math.h>

typedef _Float16 f16;
typedef f16 f16x8 __attribute__((ext_vector_type(8)));
typedef f16 f16x2 __attribute__((ext_vector_type(2)));
typedef float f32x4 __attribute__((ext_vector_type(4)));

// ---------------- problem constants ----------------
#define BB 2
#define QQ 2048
#define CF 576
#define NOFF 36
#define NBQ (BB*QQ)          // 4096
#define NROWS (NOFF*NBQ)     // 147456  (row R = bq*36 + n)
#define FEAT_ELEMS (BB*66*66*64)
#define MROWS 48             // rows per workgroup (spans exactly 2 bq segments)
#define NWG (NROWS/MROWS)    // 3072
#define PITCHB 640           // bytes per LDS X row (320 halfs)

// ---------------- kernel 1: conv 3x3, 3->64, padded NHWC, fp16 out ----------------
__global__ __launch_bounds__(256) void k_conv(const float* __restrict__ inp,
                                              const float* __restrict__ ew,
                                              const float* __restrict__ eb,
                                              f16* __restrict__ feat) {
    int idx = blockIdx.x * 256 + threadIdx.x;
    if (idx >= FEAT_ELEMS) return;
    int c = idx & 63;
    int t = idx >> 6;
    int x = t % 66; t /= 66;
    int y = t % 66;
    int b = t / 66;
    float v = 0.f;
    if (y >= 1 && y <= 64 && x >= 1 && x <= 64) {
        int yr = y - 1, xr = x - 1;
        v = eb[c];
        #pragma unroll
        for (int i = 0; i < 3; ++i)
            #pragma unroll
            for (int ky = 0; ky < 3; ++ky) {
                int yy = yr + ky - 1;
                if (yy < 0 || yy > 63) continue;
                #pragma unroll
                for (int kx = 0; kx < 3; ++kx) {
                    int xx = xr + kx - 1;
                    if (xx < 0 || xx > 63) continue;
                    v = fmaf(inp[((b*3 + i)*64 + yy)*64 + xx],
                             ew[((c*3 + i)*3 + ky)*3 + kx], v);
                }
            }
    }
    feat[idx] = (f16)v;
}

// ---------------- kernel 2: weight convert fp32 -> fp16, k-step-major ----------------
// layout [ks][N][32]: element (ks,col,kk) at (ks*N + col)*32 + kk, k = ks*32+kk
__global__ __launch_bounds__(256) void k_wcvt(const float* __restrict__ w0,
                                              const float* __restrict__ w1,
                                              const float* __restrict__ w2,
                                              const float* __restrict__ w3,
                                              const float* __restrict__ w4,
                                              f16* __restrict__ wt0, f16* __restrict__ wt1,
                                              f16* __restrict__ wt2, f16* __restrict__ wt3,
                                              f16* __restrict__ wt4) {
    int i = blockIdx.x * 256 + threadIdx.x;
    if (i < 19*256*32) {
        int kk = i & 31, col = (i >> 5) & 255, ks = i >> 13;
        int k = ks*32 + kk;
        wt0[i] = (f16)((k < 578) ? w0[k*256 + col] : 0.f);
        return;
    }
    i -= 19*256*32;
    if (i < 3*65536) {
        int l = i >> 16, j = i & 65535;
        int kk = j & 31, col = (j >> 5) & 255, ks = j >> 13;
        int k = ks*32 + kk;
        const float* w = (l == 0) ? w1 : (l == 1) ? w2 : w3;
        f16* wt = (l == 0) ? wt1 : (l == 1) ? wt2 : wt3;
        wt[j] = (f16)w[k*256 + col];
        return;
    }
    i -= 3*65536;
    if (i < 8192) {
        int kk = i & 31, col = (i >> 5) & 31, ks = i >> 10;
        int k = ks*32 + kk;
        wt4[i] = (f16)((col < 27) ? w4[k*27 + col] : 0.f);
    }
}

// ---------------- kernel 3: per-row prep (R = bq*36 + n) ----------------
__global__ __launch_bounds__(256) void k_prep(const float* __restrict__ coord,
                                              float* __restrict__ qc0w,
                                              float* __restrict__ qc1w,
                                              float* __restrict__ areaw,
                                              int* __restrict__ iposw) {
    int R = blockIdx.x * 256 + threadIdx.x;
    if (R >= NROWS) return;
    int bq = R / 36, n = R - bq*36;
    const float offs[6] = {-3.f, -2.f, -1.f, 1.f, 2.f, 3.f};
    float vx = offs[n / 6];
    float vy = offs[n % 6];
    const float* cp = coord + bq * 18;
    float cc0 = cp[8] + vx * (1.0f/64.0f) + 1e-6f;
    float cc1 = cp[9] + vy * (1.0f/64.0f) + 1e-6f;
    cc0 = fminf(fmaxf(cc0, -1.f + 1e-6f), 1.f - 1e-6f);
    cc1 = fminf(fmaxf(cc1, -1.f + 1e-6f), 1.f - 1e-6f);
    int iy = (int)rintf(((cc0 + 1.f) * 64.f - 1.f) * 0.5f);
    int ix = (int)rintf(((cc1 + 1.f) * 64.f - 1.f) * 0.5f);
    iy = min(max(iy, 0), 63);
    ix = min(max(ix, 0), 63);
    float qc0 = -1.f + (2.f * (float)iy + 1.f) * (1.0f/64.0f);
    float qc1 = -1.f + (2.f * (float)ix + 1.f) * (1.0f/64.0f);
    float rel0 = (cp[0] - qc0) * 4096.f;
    float rel1 = (cp[1] - qc1);
    qc0w[R] = qc0;
    qc1w[R] = qc1;
    areaw[R] = fabsf(rel0 * rel1) + 1e-9f;
    int b = bq >> 11;
    iposw[R] = ((b*66 + iy)*66 + ix) * 64;
}

// ---------------- kernel 4: per-bq weights (perm + normalize) ----------------
__global__ __launch_bounds__(256) void k_wgt(const float* __restrict__ areaw,
                                             float* __restrict__ wgtw) {
    int bq = blockIdx.x * 256 + threadIdx.x;
    if (bq >= NBQ) return;
    float a[36];
    float tot = 0.f;
    #pragma unroll
    for (int n = 0; n < 36; ++n) { a[n] = areaw[bq*36 + n]; tot += a[n]; }
    #pragma unroll
    for (int n = 0; n < 36; ++n) {
        int pn = (n < 4) ? 3 - n : n;
        wgtw[bq*36 + n] = a[pn] / tot;
    }
}

// ---------------- build X chunk into LDS (hw sin/cos, fp16 feat) ----------------
template <int COLS2, int JOFF>
__device__ __forceinline__ void buildX(f16* sX, const f16* __restrict__ feat,
                                       const int* s_ipos, const float* s_crd,
                                       const float* s_qc0, const float* s_qc1,
                                       const float* s_cx, const float* s_cy,
                                       const float* s_div, int tid) {
    constexpr int NPAIR = MROWS * COLS2;
    #pragma unroll 2
    for (int p = tid; p < NPAIR; p += 512) {
        int r = p / COLS2;                 // division by compile-time constant
        int j = JOFF + ((p - r * COLS2) << 1);
        float v0, v1;
        if (j < CF) {
            int c0 = j / 9,  s0 = j  - c0*9;
            int j1 = j + 1;
            int c1 = j1 / 9, s1 = j1 - c1*9;
            int ip = s_ipos[r];
            float f0 = (float)feat[ip + ((s0/3)*66 + (s0 - (s0/3)*3))*64 + c0];
            float f1 = (float)feat[ip + ((s1/3)*66 + (s1 - (s1/3)*3))*64 + c1];
            int d  = j & 63;
            int pl = j >> 6;
            int h2 = d >> 5;
            float qc = h2 ? s_qc1[r] : s_qc0[r];
            float sc = h2 ? 1.f : 4096.f;
            float comp = (s_crd[r*18 + 2*pl + h2] - qc) * sc;
            float arg  = comp * s_div[(d & 31) >> 1];
            // hw sin/cos: reduce to revolutions (same numerics as R5/R6)
            float rev = arg * 0.15915494309189535f;
            rev = rev - rintf(rev);
            v0 = f0 + __builtin_amdgcn_sinf(rev);
            v1 = f1 + __builtin_amdgcn_cosf(rev);
        } else if (j == CF) {
            v0 = s_cx[r]; v1 = s_cy[r];
        } else {
            v0 = 0.f; v1 = 0.f;
        }
        uint off = (uint)(r*PITCHB + (j - JOFF)*2);
        off ^= (uint)((r & 7) << 4);
        f16x2 hv = { (f16)v0, (f16)v1 };
        *(f16x2*)((char*)sX + off) = hv;
    }
}

// ---------------- direct-load GEMM (layer 4 only, tiny) ----------------
template <int NKS, int NNT, int PITCHC>
__device__ __forceinline__ void gemmT(const f16* sX, const f16* __restrict__ Wt,
                                      int colbase, int lg,
                                      const uint (&abase)[3], uint aswz,
                                      f32x4 (&acc)[3][NNT]) {
    #pragma unroll
    for (int ks = 0; ks < NKS; ++ks) {
        f16x8 a[3], b[NNT];
        #pragma unroll
        for (int nt = 0; nt < NNT; ++nt)
            b[nt] = *(const f16x8*)(Wt + (ks*PITCHC + colbase + nt*16)*32 + lg*8);
        #pragma unroll
        for (int mt = 0; mt < 3; ++mt)
            a[mt] = *(const f16x8*)((const char*)sX + ((abase[mt] + (uint)(ks*64)) ^ aswz));
        #pragma unroll
        for (int mt = 0; mt < 3; ++mt)
            #pragma unroll
            for (int nt = 0; nt < NNT; ++nt)
                acc[mt][nt] = __builtin_amdgcn_mfma_f32_16x16x32_f16(a[mt], b[nt], acc[mt][nt], 0, 0, 0);
    }
}

// ---------------- kernel 5: fused MFMA MLP, LDS-staged B, 8 waves ----------------
// 512 threads; wave wc=tid>>6 computes 48 rows x 32 cols (cols wc*32..+31).
// Staging done only by waves 0-3 with the R11-proven fully-coalesced pattern.
__global__ __launch_bounds__(512, 2) void k_mlp(
    const float* __restrict__ coord, const float* __restrict__ cellp,
    const f16* __restrict__ feat,
    const float* __restrict__ qc0w, const float* __restrict__ qc1w,
    const float* __restrict__ wgtw, const int* __restrict__ iposw,
    const f16* __restrict__ wt0, const f16* __restrict__ wt1,
    const f16* __restrict__ wt2, const f16* __restrict__ wt3,
    const f16* __restrict__ wt4,
    const float* __restrict__ b0, const float* __restrict__ b1,
    const float* __restrict__ b2, const float* __restrict__ b3,
    const float* __restrict__ b4,
    float* __restrict__ partial)   // [NWG][2][28]
{
    __shared__ f16 sX[MROWS * 320];      // 30720 B, in-place activation buffer
    __shared__ f16 sBB[2][8192];         // 2 x 16 KB B k-step tiles, layout [lg][col][8]
    __shared__ float s_crd[MROWS * 18];
    __shared__ float s_qc0[MROWS], s_qc1[MROWS], s_cx[MROWS], s_cy[MROWS], s_wgt[MROWS];
    __shared__ int   s_ipos[MROWS];
    __shared__ float s_div[16];

    int tid = threadIdx.x;
    int R0  = blockIdx.x * MROWS;

    if (tid < 16) s_div[tid] = expf((float)(2*tid) * -0.28782313662425575f);
    if (tid < MROWS) {
        int R  = R0 + tid;
        int bq = R / 36;
        s_qc0[tid]  = __builtin_nontemporal_load(&qc0w[R]);
        s_qc1[tid]  = __builtin_nontemporal_load(&qc1w[R]);
        s_wgt[tid]  = __builtin_nontemporal_load(&wgtw[R]);
        s_ipos[tid] = __builtin_nontemporal_load(&iposw[R]);
        s_cx[tid]   = cellp[bq*2 + 0] * 64.f;
        s_cy[tid]   = cellp[bq*2 + 1] * 64.f;
    }
    for (int i = tid; i < MROWS*18; i += 512) {
        int r = i / 18, d = i - r*18;
        s_crd[i] = coord[((R0 + r)/36)*18 + d];
    }

    int lane = tid & 63;
    int wc   = tid >> 6;    // wave = col group of 32 (0..7)
    int l15  = lane & 15;
    int lg   = lane >> 4;   // 0..3
    uint aswz = (uint)((lane & 7) << 4);

    uint abase[3];
    #pragma unroll
    for (int mt = 0; mt < 3; ++mt) {
        int row = mt*16 + l15;
        abase[mt] = (uint)(row * PITCHB + lg*16);
    }

    f32x4 acc[3][2];
    auto zacc = [&]() {
        #pragma unroll
        for (int mt = 0; mt < 3; ++mt)
            #pragma unroll
            for (int nt = 0; nt < 2; ++nt)
                #pragma unroll
                for (int i = 0; i < 4; ++i) acc[mt][nt][i] = 0.f;
    };

    // cooperative async stage (waves 0-3 only, R11 pattern): each thread loads
    // 64 B contiguous global -> 4 x 16 B LDS chunks. chunk c = lg*256+col at
    // byte c*16 holds global bytes col*64 + lg*16.
    auto stage = [&](f16* dst, const f16* __restrict__ Wt, int ks) {
        if (tid < 256) {
            const char* g = (const char*)Wt + (size_t)ks * 16384 + (size_t)tid * 64;
            char* d = (char*)dst + tid * 16;
            #pragma unroll
            for (int i = 0; i < 4; ++i) {
                __builtin_amdgcn_global_load_lds(
                    (const __attribute__((address_space(1))) void*)(g + i*16),
                    (__attribute__((address_space(3))) void*)(d + i*4096),
                    16, 0, 0);
            }
        }
    };

    // one k-step of MFMA: B frags from staged LDS tile, A frags from sX
    auto computeK = [&](const f16* sB, int lks) {
        f16x8 a[3], b[2];
        #pragma unroll
        for (int nt = 0; nt < 2; ++nt)
            b[nt] = *(const f16x8*)((const char*)sB + lg*4096 + (wc*32 + nt*16 + l15)*16);
        #pragma unroll
        for (int mt = 0; mt < 3; ++mt)
            a[mt] = *(const f16x8*)((const char*)sX + ((abase[mt] + (uint)(lks*64)) ^ aswz));
        #pragma unroll
        for (int mt = 0; mt < 3; ++mt)
            #pragma unroll
            for (int nt = 0; nt < 2; ++nt)
                acc[mt][nt] = __builtin_amdgcn_mfma_f32_16x16x32_f16(a[mt], b[nt], acc[mt][nt], 0, 0, 0);
    };

    // run nks k-steps: stage(ks+1) issued after the per-kstep barrier -> in flight
    // during compute(ks); next barrier's vmcnt drain lands it (T3-lite).
    auto runLayer = [&](const f16* __restrict__ Wt, int gksOff, int nks, int lksOff) {
        stage(sBB[0], Wt, gksOff);
        for (int ks = 0; ks < nks; ++ks) {
            __syncthreads();
            if (ks + 1 < nks) stage(sBB[(ks + 1) & 1], Wt, gksOff + ks + 1);
            computeK(sBB[ks & 1], lksOff + ks);
        }
    };

    // bias + relu + fp16 -> swizzled LDS (in place, after barrier)
    auto epi = [&](const float* __restrict__ bias) {
        #pragma unroll
        for (int nt = 0; nt < 2; ++nt) {
            int col = wc*32 + nt*16 + l15;
            float bv = bias[col];
            #pragma unroll
            for (int mt = 0; mt < 3; ++mt)
                #pragma unroll
                for (int i = 0; i < 4; ++i) {
                    int row = mt*16 + lg*4 + i;
                    float v = fmaxf(acc[mt][nt][i] + bv, 0.f);
                    uint off = (uint)(row*PITCHB + col*2) ^ (uint)((row & 7) << 4);
                    *(f16*)((char*)sX + off) = (f16)v;
                }
        }
    };

    __syncthreads();

    // ---- layer 0 : K = 608, X in two LDS chunks, in-place ----
    zacc();
    buildX<160, 0>(sX, feat, s_ipos, s_crd, s_qc0, s_qc1, s_cx, s_cy, s_div, tid);
    runLayer(wt0, 0, 10, 0);       // loop barrier covers buildX + stage(0)
    __syncthreads();               // all compute done reading X chunk 0
    buildX<144, 320>(sX, feat, s_ipos, s_crd, s_qc0, s_qc1, s_cx, s_cy, s_div, tid);
    runLayer(wt0, 10, 9, 0);
    __syncthreads();
    epi(b0);

    // ---- layers 1..3 : K = 256, in-place ----
    zacc(); runLayer(wt1, 0, 8, 0); __syncthreads(); epi(b1);
    zacc(); runLayer(wt2, 0, 8, 0); __syncthreads(); epi(b2);
    zacc(); runLayer(wt3, 0, 8, 0); __syncthreads(); epi(b3);
    __syncthreads();   // L4 reads sX

    // ---- layer 4 : 256 -> 27 (padded 32), wave 0 only, + weighted segment sums ----
    if (wc == 0) {
        f32x4 a4[3][2];
        #pragma unroll
        for (int mt = 0; mt < 3; ++mt)
            #pragma unroll
            for (int nt = 0; nt < 2; ++nt)
                #pragma unroll
                for (int i = 0; i < 4; ++i) a4[mt][nt][i] = 0.f;
        gemmT<8,2,32>(sX, wt4, l15, lg, abase, aswz, a4);
        // WG covers rows of exactly 2 bq segments: rows [0,split) and [split,48)
        int split = 36 - (R0 % 36);    // R0%36 in {0,12,24} -> split in {36,24,12}
        #pragma unroll
        for (int nt = 0; nt < 2; ++nt) {
            int col = nt*16 + l15;
            float bv = (col < 27) ? b4[col] : 0.f;
            float s0 = 0.f, s1 = 0.f;
            #pragma unroll
            for (int mt = 0; mt < 3; ++mt)
                #pragma unroll
                for (int i = 0; i < 4; ++i) {
                    int row = mt*16 + lg*4 + i;
                    float v = (a4[mt][nt][i] + bv) * s_wgt[row];
                    if (row < split) s0 += v; else s1 += v;
                }
            // reduce across lg groups (lanes +-16, +-32)
            s0 += __shfl_xor(s0, 16, 64);
            s0 += __shfl_xor(s0, 32, 64);
            s1 += __shfl_xor(s1, 16, 64);
            s1 += __shfl_xor(s1, 32, 64);
            if (lg == 0 && col < 27) {
                __builtin_nontemporal_store(s0, &partial[(size_t)blockIdx.x*56 + col]);
                __builtin_nontemporal_store(s1, &partial[(size_t)blockIdx.x*56 + 28 + col]);
            }
        }
    }
}

// ---------------- kernel 6: combine <=2 window partials per bq ----------------
__global__ __launch_bounds__(256) void k_red(const float* __restrict__ partial,
                                             float* __restrict__ out) {
    int i = blockIdx.x * 256 + threadIdx.x;
    if (i >= NBQ * 27) return;
    int bq = i / 27, col = i - bq*27;
    int r_lo = bq * 36;
    int w0 = r_lo / 48, w1 = (r_lo + 35) / 48;
    float s = 0.f;
    for (int w = w0; w <= w1; ++w) {
        int seg = (bq == (w*48)/36) ? 0 : 1;
        s += __builtin_nontemporal_load(&partial[(size_t)w*56 + seg*28 + col]);
    }
    out[i] = s;
}

// ---------------- launch ----------------
extern "C" void kernel_launch(void* const* d_in, const int* in_sizes, int n_in,
                              void* d_out, int out_size, void* d_ws, size_t ws_size,
                              hipStream_t stream) {
    const float* inp   = (const float*)d_in[0];
    const float* coord = (const float*)d_in[1];
    const float* cellp = (const float*)d_in[2];
    const float* enc_w = (const float*)d_in[3];
    const float* enc_b = (const float*)d_in[4];
    const float* w0 = (const float*)d_in[5];
    const float* b0 = (const float*)d_in[6];
    const float* w1 = (const float*)d_in[7];
    const float* b1 = (const float*)d_in[8];
    const float* w2 = (const float*)d_in[9];
    const float* b2 = (const float*)d_in[10];
    const float* w3 = (const float*)d_in[11];
    const float* b3 = (const float*)d_in[12];
    const float* w4 = (const float*)d_in[13];
    const float* b4 = (const float*)d_in[14];
    float* outp = (float*)d_out;

    float* ws    = (float*)d_ws;
    f16*   feat  = (f16*)ws;                         // FEAT_ELEMS halfs
    float* qc0w  = (float*)(feat + FEAT_ELEMS);      // NROWS
    float* qc1w  = qc0w + NROWS;
    float* areaw = qc1w + NROWS;
    float* wgtw  = areaw + NROWS;
    int*   iposw = (int*)(wgtw + NROWS);
    float* partial = (float*)(iposw + NROWS);        // NWG*2*28
    f16*   wt0   = (f16*)(partial + (size_t)NWG*56); // 19*256*32
    f16*   wt1   = wt0 + 19*256*32;
    f16*   wt2   = wt1 + 65536;
    f16*   wt3   = wt2 + 65536;
    f16*   wt4   = wt3 + 65536;                      // 8192

    k_conv<<<(FEAT_ELEMS + 255)/256, 256, 0, stream>>>(inp, enc_w, enc_b, feat);
    k_wcvt<<<1408, 256, 0, stream>>>(w0, w1, w2, w3, w4, wt0, wt1, wt2, wt3, wt4);
    k_prep<<<NROWS/256, 256, 0, stream>>>(coord, qc0w, qc1w, areaw, iposw);
    k_wgt<<<(NBQ + 255)/256, 256, 0, stream>>>(areaw, wgtw);
    k_mlp<<<NWG, 512, 0, stream>>>(coord, cellp, feat, qc0w, qc1w, wgtw, iposw,
                                   wt0, wt1, wt2, wt3, wt4,
                                   b0, b1, b2, b3, b4, partial);
    k_red<<<(NBQ*27 + 255)/256, 256, 0, stream>>>(partial, outp);
}

// Round 14
// 288.912 us; speedup vs baseline: 1.5663x; 1.0701x over previous
//
#include <hip/hip_runtime.h>
#include <math.h>

typedef _Float16 f16;
typedef f16 f16x8 __attribute__((ext_vector_type(8)));
typedef f16 f16x2 __attribute__((ext_vector_type(2)));
typedef float f32x4 __attribute__((ext_vector_type(4)));

// ---------------- problem constants ----------------
#define BB 2
#define QQ 2048
#define CF 576
#define NOFF 36
#define NBQ (BB*QQ)          // 4096
#define NROWS (NOFF*NBQ)     // 147456  (row R = bq*36 + n)
#define FEAT_ELEMS (BB*66*66*64)
#define MROWS 48             // rows per workgroup (spans exactly 2 bq segments)
#define NWG (NROWS/MROWS)    // 3072
#define PITCHB 512           // bytes per LDS X row (256 halfs)

// ---------------- kernel 1: conv 3x3, 3->64, padded NHWC, fp16 out ----------------
__global__ __launch_bounds__(256) void k_conv(const float* __restrict__ inp,
                                              const float* __restrict__ ew,
                                              const float* __restrict__ eb,
                                              f16* __restrict__ feat) {
    int idx = blockIdx.x * 256 + threadIdx.x;
    if (idx >= FEAT_ELEMS) return;
    int c = idx & 63;
    int t = idx >> 6;
    int x = t % 66; t /= 66;
    int y = t % 66;
    int b = t / 66;
    float v = 0.f;
    if (y >= 1 && y <= 64 && x >= 1 && x <= 64) {
        int yr = y - 1, xr = x - 1;
        v = eb[c];
        #pragma unroll
        for (int i = 0; i < 3; ++i)
            #pragma unroll
            for (int ky = 0; ky < 3; ++ky) {
                int yy = yr + ky - 1;
                if (yy < 0 || yy > 63) continue;
                #pragma unroll
                for (int kx = 0; kx < 3; ++kx) {
                    int xx = xr + kx - 1;
                    if (xx < 0 || xx > 63) continue;
                    v = fmaf(inp[((b*3 + i)*64 + yy)*64 + xx],
                             ew[((c*3 + i)*3 + ky)*3 + kx], v);
                }
            }
    }
    feat[idx] = (f16)v;
}

// ---------------- kernel 2: weight convert fp32 -> fp16, k-step-major ----------------
// layout [ks][N][32]: element (ks,col,kk) at (ks*N + col)*32 + kk, k = ks*32+kk
__global__ __launch_bounds__(256) void k_wcvt(const float* __restrict__ w0,
                                              const float* __restrict__ w1,
                                              const float* __restrict__ w2,
                                              const float* __restrict__ w3,
                                              const float* __restrict__ w4,
                                              f16* __restrict__ wt0, f16* __restrict__ wt1,
                                              f16* __restrict__ wt2, f16* __restrict__ wt3,
                                              f16* __restrict__ wt4) {
    int i = blockIdx.x * 256 + threadIdx.x;
    if (i < 19*256*32) {
        int kk = i & 31, col = (i >> 5) & 255, ks = i >> 13;
        int k = ks*32 + kk;
        wt0[i] = (f16)((k < 578) ? w0[k*256 + col] : 0.f);
        return;
    }
    i -= 19*256*32;
    if (i < 3*65536) {
        int l = i >> 16, j = i & 65535;
        int kk = j & 31, col = (j >> 5) & 255, ks = j >> 13;
        int k = ks*32 + kk;
        const float* w = (l == 0) ? w1 : (l == 1) ? w2 : w3;
        f16* wt = (l == 0) ? wt1 : (l == 1) ? wt2 : wt3;
        wt[j] = (f16)w[k*256 + col];
        return;
    }
    i -= 3*65536;
    if (i < 8192) {
        int kk = i & 31, col = (i >> 5) & 31, ks = i >> 10;
        int k = ks*32 + kk;
        wt4[i] = (f16)((col < 27) ? w4[k*27 + col] : 0.f);
    }
}

// ---------------- kernel 3: per-row prep (R = bq*36 + n) ----------------
__global__ __launch_bounds__(256) void k_prep(const float* __restrict__ coord,
                                              float* __restrict__ qc0w,
                                              float* __restrict__ qc1w,
                                              float* __restrict__ areaw,
                                              int* __restrict__ iposw) {
    int R = blockIdx.x * 256 + threadIdx.x;
    if (R >= NROWS) return;
    int bq = R / 36, n = R - bq*36;
    const float offs[6] = {-3.f, -2.f, -1.f, 1.f, 2.f, 3.f};
    float vx = offs[n / 6];
    float vy = offs[n % 6];
    const float* cp = coord + bq * 18;
    float cc0 = cp[8] + vx * (1.0f/64.0f) + 1e-6f;
    float cc1 = cp[9] + vy * (1.0f/64.0f) + 1e-6f;
    cc0 = fminf(fmaxf(cc0, -1.f + 1e-6f), 1.f - 1e-6f);
    cc1 = fminf(fmaxf(cc1, -1.f + 1e-6f), 1.f - 1e-6f);
    int iy = (int)rintf(((cc0 + 1.f) * 64.f - 1.f) * 0.5f);
    int ix = (int)rintf(((cc1 + 1.f) * 64.f - 1.f) * 0.5f);
    iy = min(max(iy, 0), 63);
    ix = min(max(ix, 0), 63);
    float qc0 = -1.f + (2.f * (float)iy + 1.f) * (1.0f/64.0f);
    float qc1 = -1.f + (2.f * (float)ix + 1.f) * (1.0f/64.0f);
    float rel0 = (cp[0] - qc0) * 4096.f;
    float rel1 = (cp[1] - qc1);
    qc0w[R] = qc0;
    qc1w[R] = qc1;
    areaw[R] = fabsf(rel0 * rel1) + 1e-9f;
    int b = bq >> 11;
    iposw[R] = ((b*66 + iy)*66 + ix) * 64;
}

// ---------------- kernel 4: per-bq weights (perm + normalize) ----------------
__global__ __launch_bounds__(256) void k_wgt(const float* __restrict__ areaw,
                                             float* __restrict__ wgtw) {
    int bq = blockIdx.x * 256 + threadIdx.x;
    if (bq >= NBQ) return;
    float a[36];
    float tot = 0.f;
    #pragma unroll
    for (int n = 0; n < 36; ++n) { a[n] = areaw[bq*36 + n]; tot += a[n]; }
    #pragma unroll
    for (int n = 0; n < 36; ++n) {
        int pn = (n < 4) ? 3 - n : n;
        wgtw[bq*36 + n] = a[pn] / tot;
    }
}

// ---------------- build X chunk into LDS (hw sin/cos, fp16 feat) ----------------
template <int COLS2, int JOFF>
__device__ __forceinline__ void buildX(f16* sX, const f16* __restrict__ feat,
                                       const int* s_ipos, const float* s_crd,
                                       const float* s_qc0, const float* s_qc1,
                                       const float* s_cx, const float* s_cy,
                                       const float* s_div, int tid) {
    constexpr int NPAIR = MROWS * COLS2;
    #pragma unroll 2
    for (int p = tid; p < NPAIR; p += 512) {
        int r = p / COLS2;                 // division by compile-time constant
        int j = JOFF + ((p - r * COLS2) << 1);
        float v0, v1;
        if (j < CF) {
            int c0 = j / 9,  s0 = j  - c0*9;
            int j1 = j + 1;
            int c1 = j1 / 9, s1 = j1 - c1*9;
            int ip = s_ipos[r];
            float f0 = (float)feat[ip + ((s0/3)*66 + (s0 - (s0/3)*3))*64 + c0];
            float f1 = (float)feat[ip + ((s1/3)*66 + (s1 - (s1/3)*3))*64 + c1];
            int d  = j & 63;
            int pl = j >> 6;
            int h2 = d >> 5;
            float qc = h2 ? s_qc1[r] : s_qc0[r];
            float sc = h2 ? 1.f : 4096.f;
            float comp = (s_crd[r*18 + 2*pl + h2] - qc) * sc;
            float arg  = comp * s_div[(d & 31) >> 1];
            // hw sin/cos: reduce to revolutions (same numerics as R5..R13)
            float rev = arg * 0.15915494309189535f;
            rev = rev - rintf(rev);
            v0 = f0 + __builtin_amdgcn_sinf(rev);
            v1 = f1 + __builtin_amdgcn_cosf(rev);
        } else if (j == CF) {
            v0 = s_cx[r]; v1 = s_cy[r];
        } else {
            v0 = 0.f; v1 = 0.f;
        }
        uint off = (uint)(r*PITCHB + (j - JOFF)*2);
        off ^= (uint)((r & 7) << 4);
        f16x2 hv = { (f16)v0, (f16)v1 };
        *(f16x2*)((char*)sX + off) = hv;
    }
}

// ---------------- direct-load GEMM (layer 4 only, tiny) ----------------
template <int NKS, int NNT, int PITCHC>
__device__ __forceinline__ void gemmT(const f16* sX, const f16* __restrict__ Wt,
                                      int colbase, int lg,
                                      const uint (&abase)[3], uint aswz,
                                      f32x4 (&acc)[3][NNT]) {
    #pragma unroll
    for (int ks = 0; ks < NKS; ++ks) {
        f16x8 a[3], b[NNT];
        #pragma unroll
        for (int nt = 0; nt < NNT; ++nt)
            b[nt] = *(const f16x8*)(Wt + (ks*PITCHC + colbase + nt*16)*32 + lg*8);
        #pragma unroll
        for (int mt = 0; mt < 3; ++mt)
            a[mt] = *(const f16x8*)((const char*)sX + ((abase[mt] + (uint)(ks*64)) ^ aswz));
        #pragma unroll
        for (int mt = 0; mt < 3; ++mt)
            #pragma unroll
            for (int nt = 0; nt < NNT; ++nt)
                acc[mt][nt] = __builtin_amdgcn_mfma_f32_16x16x32_f16(a[mt], b[nt], acc[mt][nt], 0, 0, 0);
    }
}

// ---------------- pipeline sync helpers (T4: counted vmcnt + raw barrier) ----------------
__device__ __forceinline__ void waitv4() {
    asm volatile("s_waitcnt vmcnt(4)" ::: "memory");
    __builtin_amdgcn_sched_barrier(0);
}
__device__ __forceinline__ void waitv0() {
    asm volatile("s_waitcnt vmcnt(0)" ::: "memory");
    __builtin_amdgcn_sched_barrier(0);
}
__device__ __forceinline__ void waitlgkm() {
    asm volatile("s_waitcnt lgkmcnt(0)" ::: "memory");
    __builtin_amdgcn_sched_barrier(0);
}
__device__ __forceinline__ void barrier() {
    __builtin_amdgcn_s_barrier();
    __builtin_amdgcn_sched_barrier(0);
}

// ---------------- kernel 5: fused MFMA MLP, depth-2 LDS staging pipeline ----------------
// 512 threads; wave wc=tid>>6 computes 48 rows x 32 cols (cols wc*32..+31).
// Staging by waves 0-3 only (R11/R13-proven coalesced pattern), 3 buffers, depth-2.
__global__ __launch_bounds__(512, 2) void k_mlp(
    const float* __restrict__ coord, const float* __restrict__ cellp,
    const f16* __restrict__ feat,
    const float* __restrict__ qc0w, const float* __restrict__ qc1w,
    const float* __restrict__ wgtw, const int* __restrict__ iposw,
    const f16* __restrict__ wt0, const f16* __restrict__ wt1,
    const f16* __restrict__ wt2, const f16* __restrict__ wt3,
    const f16* __restrict__ wt4,
    const float* __restrict__ b0, const float* __restrict__ b1,
    const float* __restrict__ b2, const float* __restrict__ b3,
    const float* __restrict__ b4,
    float* __restrict__ partial)   // [NWG][2][28]
{
    __shared__ f16 sX[MROWS * 256];      // 24576 B, in-place activation buffer (pitch 512 B)
    __shared__ f16 sBB[3][8192];         // 3 x 16 KB B k-step tiles, layout [lg][col][8]
    __shared__ float s_crd[MROWS * 18];
    __shared__ float s_qc0[MROWS], s_qc1[MROWS], s_cx[MROWS], s_cy[MROWS], s_wgt[MROWS];
    __shared__ int   s_ipos[MROWS];
    __shared__ float s_div[16];

    int tid = threadIdx.x;
    int R0  = blockIdx.x * MROWS;

    if (tid < 16) s_div[tid] = expf((float)(2*tid) * -0.28782313662425575f);
    if (tid < MROWS) {
        int R  = R0 + tid;
        int bq = R / 36;
        s_qc0[tid]  = __builtin_nontemporal_load(&qc0w[R]);
        s_qc1[tid]  = __builtin_nontemporal_load(&qc1w[R]);
        s_wgt[tid]  = __builtin_nontemporal_load(&wgtw[R]);
        s_ipos[tid] = __builtin_nontemporal_load(&iposw[R]);
        s_cx[tid]   = cellp[bq*2 + 0] * 64.f;
        s_cy[tid]   = cellp[bq*2 + 1] * 64.f;
    }
    for (int i = tid; i < MROWS*18; i += 512) {
        int r = i / 18, d = i - r*18;
        s_crd[i] = coord[((R0 + r)/36)*18 + d];
    }

    int lane = tid & 63;
    int wc   = tid >> 6;    // wave = col group of 32 (0..7)
    int l15  = lane & 15;
    int lg   = lane >> 4;   // 0..3
    uint aswz = (uint)((lane & 7) << 4);

    uint abase[3];
    #pragma unroll
    for (int mt = 0; mt < 3; ++mt) {
        int row = mt*16 + l15;
        abase[mt] = (uint)(row * PITCHB + lg*16);
    }

    // preload biases to registers (no vm loads inside the pipeline)
    float bvL[4][2], bv4[2];
    {
        const float* Bs[4] = {b0, b1, b2, b3};
        #pragma unroll
        for (int L = 0; L < 4; ++L)
            #pragma unroll
            for (int nt = 0; nt < 2; ++nt) {
                bvL[L][nt] = Bs[L][wc*32 + nt*16 + l15];
                asm volatile("" :: "v"(bvL[L][nt]));   // force early materialization
            }
        #pragma unroll
        for (int nt = 0; nt < 2; ++nt) {
            int col = nt*16 + l15;
            bv4[nt] = (col < 27) ? b4[col] : 0.f;
            asm volatile("" :: "v"(bv4[nt]));
        }
    }

    f32x4 acc[3][2];
    auto zacc = [&]() {
        #pragma unroll
        for (int mt = 0; mt < 3; ++mt)
            #pragma unroll
            for (int nt = 0; nt < 2; ++nt)
                #pragma unroll
                for (int i = 0; i < 4; ++i) acc[mt][nt][i] = 0.f;
    };

    // cooperative async stage (waves 0-3 only): 64 B contiguous global per thread
    // -> 4 x 16 B LDS chunks. chunk c = lg*256+col at byte c*16 = global col*64+lg*16.
    auto stage = [&](f16* dst, const f16* __restrict__ Wt, int ks) {
        if (tid < 256) {
            const char* g = (const char*)Wt + (size_t)ks * 16384 + (size_t)tid * 64;
            char* d = (char*)dst + tid * 16;
            #pragma unroll
            for (int i = 0; i < 4; ++i) {
                __builtin_amdgcn_global_load_lds(
                    (const __attribute__((address_space(1))) void*)(g + i*16),
                    (__attribute__((address_space(3))) void*)(d + i*4096),
                    16, 0, 0);
            }
        }
        __builtin_amdgcn_sched_barrier(0);   // pin issue point
    };

    // one k-step of MFMA: B frags from staged LDS tile, A frags from sX
    auto computeK = [&](const f16* sB, int lks) {
        f16x8 a[3], b[2];
        #pragma unroll
        for (int nt = 0; nt < 2; ++nt)
            b[nt] = *(const f16x8*)((const char*)sB + lg*4096 + (wc*32 + nt*16 + l15)*16);
        #pragma unroll
        for (int mt = 0; mt < 3; ++mt)
            a[mt] = *(const f16x8*)((const char*)sX + ((abase[mt] + (uint)(lks*64)) ^ aswz));
        #pragma unroll
        for (int mt = 0; mt < 3; ++mt)
            #pragma unroll
            for (int nt = 0; nt < 2; ++nt)
                acc[mt][nt] = __builtin_amdgcn_mfma_f32_16x16x32_f16(a[mt], b[nt], acc[mt][nt], 0, 0, 0);
    };

    // bias + relu + fp16 -> swizzled LDS (in place, after barrier)
    auto epi = [&](const float (&bv)[2]) {
        #pragma unroll
        for (int nt = 0; nt < 2; ++nt) {
            int col = wc*32 + nt*16 + l15;
            #pragma unroll
            for (int mt = 0; mt < 3; ++mt)
                #pragma unroll
                for (int i = 0; i < 4; ++i) {
                    int row = mt*16 + lg*4 + i;
                    float v = fmaxf(acc[mt][nt][i] + bv[nt], 0.f);
                    uint off = (uint)(row*PITCHB + col*2) ^ (uint)((row & 7) << 4);
                    *(f16*)((char*)sX + off) = (f16)v;
                }
        }
    };

    __syncthreads();   // header ready (no stages outstanding yet)

    // ================= layer 0 : K = 608 = 19 ksteps, X in 3 chunks =================
    zacc();
    buildX<128, 0>(sX, feat, s_ipos, s_crd, s_qc0, s_qc1, s_cx, s_cy, s_div, tid);
    stage(sBB[0], wt0, 0);
    stage(sBB[1], wt0, 1);
    waitlgkm(); barrier();
    #pragma unroll
    for (int ks = 0; ks < 8; ++ks) {
        waitv4();                       // ks+1 <= 8 < 19 always in flight
        barrier();
        stage(sBB[(ks + 2) % 3], wt0, ks + 2);   // ks+2 <= 9 < 19
        computeK(sBB[ks % 3], ks);
    }
    barrier();                          // all waves done reading sX chunk 0
    buildX<128, 256>(sX, feat, s_ipos, s_crd, s_qc0, s_qc1, s_cx, s_cy, s_div, tid);
    waitlgkm(); barrier();
    #pragma unroll
    for (int t = 0; t < 8; ++t) {
        int ks = t + 8;                 // 8..15
        waitv4();
        barrier();
        stage(sBB[(ks + 2) % 3], wt0, ks + 2);   // 10..17
        computeK(sBB[ks % 3], t);
    }
    barrier();
    buildX<48, 512>(sX, feat, s_ipos, s_crd, s_qc0, s_qc1, s_cx, s_cy, s_div, tid);
    waitlgkm(); barrier();
    #pragma unroll
    for (int t = 0; t < 3; ++t) {
        int ks = t + 16;                // 16..18
        if (ks + 1 < 19) waitv4(); else waitv0();
        barrier();
        if (ks + 2 < 19) stage(sBB[(ks + 2) % 3], wt0, ks + 2);   // 18
        computeK(sBB[ks % 3], t);
    }

    // ================= layers 1..3 : K = 256 = 8 ksteps each =================
    const f16* Ws[3] = {wt1, wt2, wt3};
    #pragma unroll
    for (int L = 0; L < 3; ++L) {
        barrier();                      // all compute of prev layer done
        stage(sBB[0], Ws[L], 0);        // prologue hidden under epi
        stage(sBB[1], Ws[L], 1);
        epi(bvL[L]);                    // overwrites sX in place
        zacc();
        waitlgkm(); barrier();
        #pragma unroll
        for (int ks = 0; ks < 8; ++ks) {
            if (ks + 1 < 8) waitv4(); else waitv0();
            barrier();
            if (ks + 2 < 8) stage(sBB[(ks + 2) % 3], Ws[L], ks + 2);
            computeK(sBB[ks % 3], ks);
        }
    }
    barrier();
    epi(bvL[3]);
    waitlgkm(); barrier();              // L4 reads sX

    // ---- layer 4 : 256 -> 27 (padded 32), wave 0 only, + weighted segment sums ----
    if (wc == 0) {
        f32x4 a4[3][2];
        #pragma unroll
        for (int mt = 0; mt < 3; ++mt)
            #pragma unroll
            for (int nt = 0; nt < 2; ++nt)
                #pragma unroll
                for (int i = 0; i < 4; ++i) a4[mt][nt][i] = 0.f;
        gemmT<8,2,32>(sX, wt4, l15, lg, abase, aswz, a4);
        // WG covers rows of exactly 2 bq segments: rows [0,split) and [split,48)
        int split = 36 - (R0 % 36);    // R0%36 in {0,12,24} -> split in {36,24,12}
        #pragma unroll
        for (int nt = 0; nt < 2; ++nt) {
            int col = nt*16 + l15;
            float s0 = 0.f, s1 = 0.f;
            #pragma unroll
            for (int mt = 0; mt < 3; ++mt)
                #pragma unroll
                for (int i = 0; i < 4; ++i) {
                    int row = mt*16 + lg*4 + i;
                    float v = (a4[mt][nt][i] + bv4[nt]) * s_wgt[row];
                    if (row < split) s0 += v; else s1 += v;
                }
            // reduce across lg groups (lanes +-16, +-32)
            s0 += __shfl_xor(s0, 16, 64);
            s0 += __shfl_xor(s0, 32, 64);
            s1 += __shfl_xor(s1, 16, 64);
            s1 += __shfl_xor(s1, 32, 64);
            if (lg == 0 && col < 27) {
                __builtin_nontemporal_store(s0, &partial[(size_t)blockIdx.x*56 + col]);
                __builtin_nontemporal_store(s1, &partial[(size_t)blockIdx.x*56 + 28 + col]);
            }
        }
    }
}

// ---------------- kernel 6: combine <=2 window partials per bq ----------------
__global__ __launch_bounds__(256) void k_red(const float* __restrict__ partial,
                                             float* __restrict__ out) {
    int i = blockIdx.x * 256 + threadIdx.x;
    if (i >= NBQ * 27) return;
    int bq = i / 27, col = i - bq*27;
    int r_lo = bq * 36;
    int w0 = r_lo / 48, w1 = (r_lo + 35) / 48;
    float s = 0.f;
    for (int w = w0; w <= w1; ++w) {
        int seg = (bq == (w*48)/36) ? 0 : 1;
        s += __builtin_nontemporal_load(&partial[(size_t)w*56 + seg*28 + col]);
    }
    out[i] = s;
}

// ---------------- launch ----------------
extern "C" void kernel_launch(void* const* d_in, const int* in_sizes, int n_in,
                              void* d_out, int out_size, void* d_ws, size_t ws_size,
                              hipStream_t stream) {
    const float* inp   = (const float*)d_in[0];
    const float* coord = (const float*)d_in[1];
    const float* cellp = (const float*)d_in[2];
    const float* enc_w = (const float*)d_in[3];
    const float* enc_b = (const float*)d_in[4];
    const float* w0 = (const float*)d_in[5];
    const float* b0 = (const float*)d_in[6];
    const float* w1 = (const float*)d_in[7];
    const float* b1 = (const float*)d_in[8];
    const float* w2 = (const float*)d_in[9];
    const float* b2 = (const float*)d_in[10];
    const float* w3 = (const float*)d_in[11];
    const float* b3 = (const float*)d_in[12];
    const float* w4 = (const float*)d_in[13];
    const float* b4 = (const float*)d_in[14];
    float* outp = (float*)d_out;

    float* ws    = (float*)d_ws;
    f16*   feat  = (f16*)ws;                         // FEAT_ELEMS halfs
    float* qc0w  = (float*)(feat + FEAT_ELEMS);      // NROWS
    float* qc1w  = qc0w + NROWS;
    float* areaw = qc1w + NROWS;
    float* wgtw  = areaw + NROWS;
    int*   iposw = (int*)(wgtw + NROWS);
    float* partial = (float*)(iposw + NROWS);        // NWG*2*28
    f16*   wt0   = (f16*)(partial + (size_t)NWG*56); // 19*256*32
    f16*   wt1   = wt0 + 19*256*32;
    f16*   wt2   = wt1 + 65536;
    f16*   wt3   = wt2 + 65536;
    f16*   wt4   = wt3 + 65536;                      // 8192

    k_conv<<<(FEAT_ELEMS + 255)/256, 256, 0, stream>>>(inp, enc_w, enc_b, feat);
    k_wcvt<<<1408, 256, 0, stream>>>(w0, w1, w2, w3, w4, wt0, wt1, wt2, wt3, wt4);
    k_prep<<<NROWS/256, 256, 0, stream>>>(coord, qc0w, qc1w, areaw, iposw);
    k_wgt<<<(NBQ + 255)/256, 256, 0, stream>>>(areaw, wgtw);
    k_mlp<<<NWG, 512, 0, stream>>>(coord, cellp, feat, qc0w, qc1w, wgtw, iposw,
                                   wt0, wt1, wt2, wt3, wt4,
                                   b0, b1, b2, b3, b4, partial);
    k_red<<<(NBQ*27 + 255)/256, 256, 0, stream>>>(partial, outp);
}